// Round 1
// baseline (277.543 us; speedup 1.0000x reference)
//
#include <hip/hip_runtime.h>
#include <hip/hip_bf16.h>

typedef __attribute__((ext_vector_type(8))) short short8;
typedef __attribute__((ext_vector_type(4))) float f32x4;

namespace {
constexpr int D    = 128;
constexpr int SEQ  = 512;
constexpr int NV   = 100000;
constexpr int NN   = 2048;
constexpr int KC   = 128;                    // keys per LDS chunk
constexpr int CHUNK_B = KC * D * 2;          // 32768 B
constexpr int NCHUNK  = (NV + KC - 1) / KC;  // 782
constexpr int CPS     = 13;                  // chunks per V-slice
constexpr int NSLICE  = (NCHUNK + CPS - 1) / CPS;  // 61
constexpr float LOG2E = 1.4426950408889634f;
constexpr float EPSN  = 1e-12f;
}

// ---------------------------------------------------------------------------
// Prep: normalize keys -> bf16 Kn[V][128]; gather+normalize queries scaled by
// log2(e) -> bf16 Qn[N][128]. One wave per row.
// ---------------------------------------------------------------------------
__global__ void prep_kernel(const float* __restrict__ qemb,
                            const float* __restrict__ kemb,
                            const int*   __restrict__ loc,
                            __hip_bfloat16* __restrict__ Kn,
                            __hip_bfloat16* __restrict__ Qn)
{
    int wave = (blockIdx.x * blockDim.x + threadIdx.x) >> 6;
    int lane = threadIdx.x & 63;
    if (wave >= NV + NN) return;

    const float* src;
    __hip_bfloat16* dst;
    float extra;
    if (wave < NV) {
        src = kemb + (size_t)wave * D;
        dst = Kn + (size_t)wave * D;
        extra = 1.0f;
    } else {
        int n = wave - NV;
        int b = loc[2 * n], s = loc[2 * n + 1];
        src = qemb + ((size_t)b * SEQ + s) * D;
        dst = Qn + (size_t)n * D;
        extra = LOG2E;
    }
    float2 v = *(const float2*)(src + lane * 2);
    float ss = v.x * v.x + v.y * v.y;
    #pragma unroll
    for (int m = 1; m < 64; m <<= 1) ss += __shfl_xor(ss, m);
    float inv = extra / fmaxf(sqrtf(ss), EPSN);
    __hip_bfloat162 o;
    o.x = __float2bfloat16(v.x * inv);
    o.y = __float2bfloat16(v.y * inv);
    *(__hip_bfloat162*)(dst + lane * 2) = o;
}

// ---------------------------------------------------------------------------
// Main: per block, 256 Q-rows (4 waves x 64 rows, A-frags in registers),
// stream a V-slice of keys through double-buffered LDS chunks of 128 keys.
// logits = Q.K^T via mfma_f32_16x16x32_bf16; rowsum += exp2(logit).
// XOR-swizzled LDS ( byte ^= ((keyrow&7)<<4) ) on both write and read.
// ---------------------------------------------------------------------------
__global__ __launch_bounds__(256, 2)
void lse_main(const __hip_bfloat16* __restrict__ Kn,
              const __hip_bfloat16* __restrict__ Qn,
              float* __restrict__ sums)
{
    __shared__ char lds[2 * CHUNK_B];   // 64 KB
    const int tid  = threadIdx.x;
    const int lane = tid & 63;
    const int lr   = lane & 15;
    const int lh   = lane >> 4;
    const int w    = tid >> 6;
    const int mblk  = blockIdx.x;   // 0..7
    const int slice = blockIdx.y;   // 0..NSLICE-1

    const int chunk0 = slice * CPS;
    const int nch = min(CPS, NCHUNK - chunk0);
    const int m0 = mblk * 256 + w * 64;

    // A-operand (Q) fragments: rows m0+rg*16+lr, k = ds*32 + lh*8 .. +8
    short8 qf[4][4];
    #pragma unroll
    for (int rg = 0; rg < 4; ++rg)
        #pragma unroll
        for (int ds = 0; ds < 4; ++ds)
            qf[rg][ds] = *(const short8*)((const short*)Qn +
                          (size_t)(m0 + rg * 16 + lr) * D + ds * 32 + lh * 8);

    float rowsum[4][4] = {};
    const char* kbase = (const char*)Kn;

    if (nch > 0) {
        short8 st[8];
        // prologue: load + write chunk0 into buf0
        {
            int keybase = chunk0 * KC;
            #pragma unroll
            for (int r = 0; r < 8; ++r) {
                int linear = r * 4096 + tid * 16;
                int key = min(keybase + (linear >> 8), NV - 1);
                st[r] = *(const short8*)(kbase + (size_t)key * 256 + (linear & 255));
            }
            #pragma unroll
            for (int r = 0; r < 8; ++r) {
                int linear = r * 4096 + tid * 16;
                int phys = linear ^ (((linear >> 8) & 7) << 4);
                *(short8*)(lds + phys) = st[r];
            }
        }
        __syncthreads();

        int cur = 0;
        for (int c = 0; c < nch; ++c) {
            const bool hasnext = (c + 1 < nch);
            if (hasnext) {   // issue next chunk's global loads early (T14)
                int keybase = (chunk0 + c + 1) * KC;
                #pragma unroll
                for (int r = 0; r < 8; ++r) {
                    int linear = r * 4096 + tid * 16;
                    int key = min(keybase + (linear >> 8), NV - 1);
                    st[r] = *(const short8*)(kbase + (size_t)key * 256 + (linear & 255));
                }
            }
            // compute on buf[cur]
            const char* buf = lds + cur * CHUNK_B;
            const int vbase = (chunk0 + c) * KC;
            const bool full = (vbase + KC <= NV);
            #pragma unroll
            for (int kg = 0; kg < 8; ++kg) {
                const int kic = kg * 16 + lr;      // key row within chunk
                const int rxor = (kic & 7) << 4;
                short8 bf[4];
                #pragma unroll
                for (int ds = 0; ds < 4; ++ds) {
                    int logical = kic * 256 + ds * 64 + lh * 16;
                    bf[ds] = *(const short8*)(buf + (logical ^ rxor));
                }
                f32x4 acc[4];
                #pragma unroll
                for (int rg = 0; rg < 4; ++rg) {
                    f32x4 a = {0.f, 0.f, 0.f, 0.f};
                    #pragma unroll
                    for (int ds = 0; ds < 4; ++ds)
                        a = __builtin_amdgcn_mfma_f32_16x16x32_bf16(qf[rg][ds], bf[ds], a, 0, 0, 0);
                    acc[rg] = a;
                }
                if (full) {
                    #pragma unroll
                    for (int rg = 0; rg < 4; ++rg)
                        #pragma unroll
                        for (int j = 0; j < 4; ++j)
                            rowsum[rg][j] += __builtin_amdgcn_exp2f(acc[rg][j]);
                } else {
                    const bool ok = (vbase + kg * 16 + lr) < NV;
                    #pragma unroll
                    for (int rg = 0; rg < 4; ++rg)
                        #pragma unroll
                        for (int j = 0; j < 4; ++j)
                            rowsum[rg][j] += ok ? __builtin_amdgcn_exp2f(acc[rg][j]) : 0.f;
                }
            }
            if (hasnext) {   // write-late into the other buffer
                char* obuf = lds + (cur ^ 1) * CHUNK_B;
                #pragma unroll
                for (int r = 0; r < 8; ++r) {
                    int linear = r * 4096 + tid * 16;
                    int phys = linear ^ (((linear >> 8) & 7) << 4);
                    *(short8*)(obuf + phys) = st[r];
                }
            }
            __syncthreads();
            cur ^= 1;
        }
    }

    // reduce partial sums across the 16 column-lanes, one atomic per row
    #pragma unroll
    for (int rg = 0; rg < 4; ++rg)
        #pragma unroll
        for (int j = 0; j < 4; ++j) {
            float v = rowsum[rg][j];
            v += __shfl_xor(v, 1);
            v += __shfl_xor(v, 2);
            v += __shfl_xor(v, 4);
            v += __shfl_xor(v, 8);
            if (lr == 0)
                atomicAdd(&sums[m0 + rg * 16 + lh * 4 + j], v);
        }
}

// ---------------------------------------------------------------------------
// tgt[n] = <q_n, k_label>/(|q_n||k_label|) in full fp32. One wave per n.
// ---------------------------------------------------------------------------
__global__ void tgt_kernel(const float* __restrict__ qemb,
                           const float* __restrict__ kemb,
                           const int*   __restrict__ loc,
                           const int*   __restrict__ labels,
                           float* __restrict__ tgt)
{
    int n = (blockIdx.x * blockDim.x + threadIdx.x) >> 6;
    int lane = threadIdx.x & 63;
    if (n >= NN) return;
    int b = loc[2 * n], s = loc[2 * n + 1];
    const float* q = qemb + ((size_t)b * SEQ + s) * D;
    const float* k = kemb + (size_t)labels[n] * D;
    float2 qv = *(const float2*)(q + lane * 2);
    float2 kv = *(const float2*)(k + lane * 2);
    float qq = qv.x * qv.x + qv.y * qv.y;
    float kk = kv.x * kv.x + kv.y * kv.y;
    float qk = qv.x * kv.x + qv.y * kv.y;
    #pragma unroll
    for (int m = 1; m < 64; m <<= 1) {
        qq += __shfl_xor(qq, m);
        kk += __shfl_xor(kk, m);
        qk += __shfl_xor(qk, m);
    }
    if (lane == 0)
        tgt[n] = qk / (fmaxf(sqrtf(qq), EPSN) * fmaxf(sqrtf(kk), EPSN));
}

// ---------------------------------------------------------------------------
// Final: out = mean( log(sums[n]) - tgt[n] )
// ---------------------------------------------------------------------------
__global__ void final_kernel(const float* __restrict__ sums,
                             const float* __restrict__ tgt,
                             float* __restrict__ out)
{
    __shared__ float wsum[4];
    int t = threadIdx.x;
    float acc = 0.f;
    for (int n = t; n < NN; n += 256)
        acc += logf(sums[n]) - tgt[n];
    #pragma unroll
    for (int m = 1; m < 64; m <<= 1) acc += __shfl_xor(acc, m);
    if ((t & 63) == 0) wsum[t >> 6] = acc;
    __syncthreads();
    if (t == 0) out[0] = (wsum[0] + wsum[1] + wsum[2] + wsum[3]) / (float)NN;
}

// ---------------------------------------------------------------------------
extern "C" void kernel_launch(void* const* d_in, const int* in_sizes, int n_in,
                              void* d_out, int out_size, void* d_ws, size_t ws_size,
                              hipStream_t stream)
{
    const float* qemb   = (const float*)d_in[0];
    const float* kemb   = (const float*)d_in[1];
    const int*   loc    = (const int*)d_in[2];
    const int*   labels = (const int*)d_in[3];
    float* out = (float*)d_out;

    char* ws = (char*)d_ws;
    __hip_bfloat16* Kn = (__hip_bfloat16*)ws;
    size_t off = (size_t)NV * D * 2;                       // 25.6 MB
    __hip_bfloat16* Qn = (__hip_bfloat16*)(ws + off);
    off += (size_t)NN * D * 2;                             // +0.5 MB
    float* sums = (float*)(ws + off); off += (size_t)NN * 4;
    float* tgt  = (float*)(ws + off); off += (size_t)NN * 4;

    hipMemsetAsync(sums, 0, NN * sizeof(float), stream);

    {
        int waves  = NV + NN;
        int blocks = (waves + 3) / 4;
        prep_kernel<<<blocks, 256, 0, stream>>>(qemb, kemb, loc, Kn, Qn);
    }
    {
        dim3 grid(8, NSLICE);
        lse_main<<<grid, 256, 0, stream>>>(Kn, Qn, sums);
    }
    tgt_kernel<<<(NN * 64 + 255) / 256, 256, 0, stream>>>(qemb, kemb, loc, labels, tgt);
    final_kernel<<<1, 256, 0, stream>>>(sums, tgt, out);
}